// Round 4
// baseline (165.732 us; speedup 1.0000x reference)
//
#include <hip/hip_runtime.h>
#include <math.h>
#include <stdint.h>

#define NPTS 35937        // 33^3
#define HID 256
#define TPB 256

typedef __attribute__((ext_vector_type(8))) short short8;
typedef __attribute__((ext_vector_type(4))) float f32x4;

// ---------- helpers ----------
__device__ __forceinline__ float fast_tanh(float x) {
    float e = __expf(2.0f * x);
    return 1.0f - __fdividef(2.0f, e + 1.0f);
}

__device__ __forceinline__ short f2bf(float f) {   // RNE float->bf16
    union { float f; unsigned u; } v; v.f = f;
    unsigned r = (v.u + 0x7fffu + ((v.u >> 16) & 1u)) >> 16;
    return (short)r;
}

// order-preserving float<->uint transforms (for atomic min/max on floats)
__device__ __forceinline__ unsigned f2ord(float f) {
    unsigned u = __float_as_uint(f);
    return (u & 0x80000000u) ? ~u : (u | 0x80000000u);
}
__device__ __forceinline__ float ord2f(unsigned o) {
    unsigned u = (o & 0x80000000u) ? (o & 0x7fffffffu) : ~o;
    return __uint_as_float(u);
}

// ---------- workspace layout (bytes) ----------
// P      [0, 417792)            bf16 packed weights
// lut4   [417792, 992784)       fp32x4 LUT (35937 * 16 B)
// rng    [992784, 992792)       {ordered-min, ordered-max} of LUT values
// cells  [1048576, 2097152)     packed cells: 32^3 cells * 8 corners * 4 B
#define W1P_OFF 8192
#define W2P_OFF 73728
#define W3P_OFF 139264
#define W4P_OFF 204800
#define LUT_BYTE_OFF 417792
#define RNG_BYTE_OFF 992784
#define CELL_BYTE_OFF 1048576

__global__ __launch_bounds__(256) void pack_weights_kernel(
    const float* __restrict__ W0, const float* __restrict__ W1,
    const float* __restrict__ W2, const float* __restrict__ W3,
    const float* __restrict__ W4, short* __restrict__ P,
    unsigned* __restrict__ rng)
{
    int id = blockIdx.x * 256 + threadIdx.x;
    if (id == 0) { rng[0] = 0xFFFFFFFFu; rng[1] = 0u; }   // init min/max slots each call
    if (id >= 26112) return;
    const float* W; int f, NT, KREAL, NROW; long pbase;
    if (id < 1024)       { W = W0; f = id;         NT = 16; KREAL = 11;  NROW = 256; pbase = 0; }
    else if (id < 9216)  { W = W1; f = id - 1024;  NT = 16; KREAL = 256; NROW = 256; pbase = W1P_OFF; }
    else if (id < 17408) { W = W2; f = id - 9216;  NT = 16; KREAL = 256; NROW = 256; pbase = W2P_OFF; }
    else if (id < 25600) { W = W3; f = id - 17408; NT = 16; KREAL = 256; NROW = 256; pbase = W3P_OFF; }
    else                 { W = W4; f = id - 25600; NT = 1;  KREAL = 256; NROW = 3;   pbase = W4P_OFF; }
    int lane = f & 63;
    int tile = f >> 6;
    int nt = tile % NT, kt = tile / NT;
    int n  = nt * 16 + (lane & 15);
    int k0 = kt * 32 + ((lane >> 4) & 3) * 8;
    short v[8];
    #pragma unroll
    for (int j = 0; j < 8; ++j) {
        int k = k0 + j;
        float x = (k < KREAL && n < NROW) ? W[k * NROW + n] : 0.0f;
        v[j] = f2bf(x);
    }
    *(short8*)(P + pbase + (long)f * 8) = *(short8*)v;
}

// ---------- fused MLP via MFMA: 64 rows/block (32 points x 2 variants) ----------
#define HSTR 264   // bf16 row stride: 528 B -> row-lanes spread over 8 disjoint bank-quads

__global__ __launch_bounds__(256) void nilut_mfma_kernel(
    const float* __restrict__ param, const short* __restrict__ P,
    const float* __restrict__ b0, const float* __restrict__ b1,
    const float* __restrict__ b2, const float* __restrict__ b3,
    const float* __restrict__ b4, float* __restrict__ lut4,
    unsigned* __restrict__ rng)
{
    __shared__ short Hs[64][HSTR];   // hidden activations, bf16
    __shared__ short Is[64][40];     // layer-0 input rows (K padded to 32)
    __shared__ float OB[64][4];      // layer-4 outputs

    const int t = threadIdx.x;
    const int pblock = blockIdx.x * 32;
    const int lane = t & 63;
    const int wid  = t >> 6;        // 0..3
    const int lr = lane & 15;
    const int hi = lane >> 4;       // 0..3
    const int k8 = hi * 8;

    if (t < 64) {
        int pn = pblock + (t >> 1);
        if (pn >= NPTS) pn = NPTS - 1;
        int v = t & 1;
        int ii = pn / 1089;
        int rem = pn - ii * 1089;
        int jj = rem / 33;
        int kk = rem - jj * 33;
        float r = kk * (1.0f / 32.0f);
        float g = jj * (1.0f / 32.0f);
        float b = ii * (1.0f / 32.0f);
        float lo = fminf(r, fminf(g, b));
        float hv = fmaxf(r, fmaxf(g, b));
        float mid = r + g + b - lo - hv;    // exact: multiples of 1/32
        Is[t][0] = f2bf(r); Is[t][1] = f2bf(g); Is[t][2] = f2bf(b);
        #pragma unroll
        for (int q = 0; q < 5; ++q)
            Is[t][3 + q] = (v == 0) ? f2bf(param[q]) : (short)0;
        Is[t][8] = f2bf(lo); Is[t][9] = f2bf(mid); Is[t][10] = f2bf(hv);
        #pragma unroll
        for (int q = 11; q < 40; ++q) Is[t][q] = (short)0;
    }
    __syncthreads();

    f32x4 acc[4][4];

    // ---- layer 0: (K=32 padded) -> 256, relu ----
    {
        #pragma unroll
        for (int c = 0; c < 4; ++c) {
            float bv = b0[wid * 64 + c * 16 + lr];
            f32x4 in = {bv, bv, bv, bv};
            #pragma unroll
            for (int rt = 0; rt < 4; ++rt) acc[rt][c] = in;
        }
        short8 a[4], bfr[4];
        #pragma unroll
        for (int rt = 0; rt < 4; ++rt) a[rt] = *(const short8*)&Is[rt * 16 + lr][k8];
        #pragma unroll
        for (int c = 0; c < 4; ++c)
            bfr[c] = *(const short8*)(P + ((long)(wid * 4 + c) * 64 + lane) * 8);
        #pragma unroll
        for (int rt = 0; rt < 4; ++rt)
            #pragma unroll
            for (int c = 0; c < 4; ++c)
                acc[rt][c] = __builtin_amdgcn_mfma_f32_16x16x32_bf16(a[rt], bfr[c], acc[rt][c], 0, 0, 0);
        #pragma unroll
        for (int rt = 0; rt < 4; ++rt)
            #pragma unroll
            for (int c = 0; c < 4; ++c)
                #pragma unroll
                for (int q = 0; q < 4; ++q)
                    Hs[rt * 16 + hi * 4 + q][wid * 64 + c * 16 + lr] = f2bf(fmaxf(acc[rt][c][q], 0.0f));
    }
    __syncthreads();

    // ---- layers 1..3: 256 -> 256, tanh ----
    const long loff[3] = {W1P_OFF, W2P_OFF, W3P_OFF};
    const float* bptr[3];
    bptr[0] = b1; bptr[1] = b2; bptr[2] = b3;
    for (int L = 0; L < 3; ++L) {
        const short* WL = P + loff[L];
        const float* bb = bptr[L];
        #pragma unroll
        for (int c = 0; c < 4; ++c) {
            float bv = bb[wid * 64 + c * 16 + lr];
            f32x4 in = {bv, bv, bv, bv};
            #pragma unroll
            for (int rt = 0; rt < 4; ++rt) acc[rt][c] = in;
        }
        #pragma unroll
        for (int kt = 0; kt < 8; ++kt) {
            short8 a[4], bfr[4];
            #pragma unroll
            for (int rt = 0; rt < 4; ++rt)
                a[rt] = *(const short8*)&Hs[rt * 16 + lr][kt * 32 + k8];
            #pragma unroll
            for (int c = 0; c < 4; ++c)
                bfr[c] = *(const short8*)(WL + ((long)(kt * 16 + wid * 4 + c) * 64 + lane) * 8);
            #pragma unroll
            for (int rt = 0; rt < 4; ++rt)
                #pragma unroll
                for (int c = 0; c < 4; ++c)
                    acc[rt][c] = __builtin_amdgcn_mfma_f32_16x16x32_bf16(a[rt], bfr[c], acc[rt][c], 0, 0, 0);
        }
        __syncthreads();
        #pragma unroll
        for (int rt = 0; rt < 4; ++rt)
            #pragma unroll
            for (int c = 0; c < 4; ++c)
                #pragma unroll
                for (int q = 0; q < 4; ++q)
                    Hs[rt * 16 + hi * 4 + q][wid * 64 + c * 16 + lr] = f2bf(fast_tanh(acc[rt][c][q]));
        __syncthreads();
    }

    // ---- layer 4: 256 -> 3 (N padded to 16); wave wid owns row-tile wid ----
    {
        float bv = (lr < 3) ? b4[lr] : 0.0f;
        f32x4 a4 = {bv, bv, bv, bv};
        const short* WL = P + W4P_OFF;
        #pragma unroll
        for (int kt = 0; kt < 8; ++kt) {
            short8 a = *(const short8*)&Hs[wid * 16 + lr][kt * 32 + k8];
            short8 b = *(const short8*)(WL + ((long)kt * 64 + lane) * 8);
            a4 = __builtin_amdgcn_mfma_f32_16x16x32_bf16(a, b, a4, 0, 0, 0);
        }
        if (lr < 3) {
            #pragma unroll
            for (int q = 0; q < 4; ++q)
                OB[wid * 16 + hi * 4 + q][lr] = a4[q];
        }
    }
    __syncthreads();

    // out[n][c] = net(inp) - net(zero_inp) + identity rgb; track global min/max
    float vmn = INFINITY, vmx = -INFINITY;
    if (t < 96) {
        int pl = t / 3, c = t - pl * 3;
        int n = pblock + pl;
        if (n < NPTS) {
            int ii = n / 1089;
            int rem = n - ii * 1089;
            int jj = rem / 33;
            int kk = rem - jj * 33;
            float rgb = (c == 0) ? kk * (1.0f / 32.0f)
                      : (c == 1) ? jj * (1.0f / 32.0f)
                                 : ii * (1.0f / 32.0f);
            float val = OB[2 * pl][c] - OB[2 * pl + 1][c] + rgb;
            lut4[n * 4 + c] = val;
            vmn = val; vmx = val;
        }
    }
    // wave butterfly reduce (all 256 threads participate; inactive hold +/-inf)
    #pragma unroll
    for (int off = 32; off; off >>= 1) {
        vmn = fminf(vmn, __shfl_xor(vmn, off));
        vmx = fmaxf(vmx, __shfl_xor(vmx, off));
    }
    if (lane == 0 && vmn <= vmx) {
        atomicMin(&rng[0], f2ord(vmn));
        atomicMax(&rng[1], f2ord(vmx));
    }
}

// ---------- cell expansion: 32^3 cells, 8 corners, 32-bit word/corner ----------
// word = c0 | (c1<<11) | (c2<<22);  c0,c1: 11-bit, c2: 10-bit codes over [mn, mx]
__global__ __launch_bounds__(256) void expand_cells_kernel(
    const float* __restrict__ lut4, const unsigned* __restrict__ rng,
    unsigned* __restrict__ cells)
{
    int id = blockIdx.x * 256 + threadIdx.x;     // cell*8 + corner
    if (id >= 32768 * 8) return;
    int corner = id & 7;
    int cell   = id >> 3;
    int ir = cell & 31, ig = (cell >> 5) & 31, ib = cell >> 10;
    int dr = corner & 1, dg = (corner >> 1) & 1, db = (corner >> 2) & 1;
    int src = (ib + db) * 1089 + (ig + dg) * 33 + (ir + dr);
    float4 v = *(const float4*)(lut4 + (long)src * 4);

    float mn = ord2f(rng[0]);
    float mx = ord2f(rng[1]);
    float span = fmaxf(mx - mn, 1e-9f);
    float i01 = 2047.0f / span;
    float i2  = 1023.0f / span;

    unsigned c0 = __float2uint_rn(fmaxf(v.x - mn, 0.0f) * i01); c0 = min(c0, 2047u);
    unsigned c1 = __float2uint_rn(fmaxf(v.y - mn, 0.0f) * i01); c1 = min(c1, 2047u);
    unsigned c2 = __float2uint_rn(fmaxf(v.z - mn, 0.0f) * i2);  c2 = min(c2, 1023u);
    cells[(long)cell * 8 + corner] = c0 | (c1 << 11) | (c2 << 22);
}

// ---------- trilinear apply from packed cells (2 x 16B loads per pixel) ----------
#define LERP(a, b, f) fmaf((f), (b) - (a), (a))
#define CH0(w) ((float)((w) & 2047u))
#define CH1(w) ((float)(((w) >> 11) & 2047u))
#define CH2(w) ((float)((w) >> 22))

__global__ __launch_bounds__(256) void apply_lut_kernel(
    const float* __restrict__ img, const unsigned* __restrict__ cells,
    const unsigned* __restrict__ rng, float* __restrict__ out)
{
    const int NP = 2160 * 3840;
    int idx = blockIdx.x * blockDim.x + threadIdx.x;
    int p = idx * 4;
    if (p >= NP) return;

    float mn = ord2f(rng[0]);
    float mx = ord2f(rng[1]);
    float span = fmaxf(mx - mn, 1e-9f);
    float st01 = span * (1.0f / 2047.0f);
    float st2  = span * (1.0f / 1023.0f);

    float4 rv = *(const float4*)(img + p);
    float4 gv = *(const float4*)(img + NP + p);
    float4 bv = *(const float4*)(img + 2 * NP + p);

    float rr[4] = {rv.x, rv.y, rv.z, rv.w};
    float gg[4] = {gv.x, gv.y, gv.z, gv.w};
    float bb[4] = {bv.x, bv.y, bv.z, bv.w};
    float ox[4], oy[4], oz[4];

    #pragma unroll
    for (int u = 0; u < 4; ++u) {
        float sr = rr[u] * 32.0f, sg = gg[u] * 32.0f, sb = bb[u] * 32.0f;
        float fir = fminf(fmaxf(floorf(sr), 0.0f), 31.0f);
        float fig = fminf(fmaxf(floorf(sg), 0.0f), 31.0f);
        float fib = fminf(fmaxf(floorf(sb), 0.0f), 31.0f);
        float fr = sr - fir, fg = sg - fig, fb = sb - fib;
        int ir = (int)fir, ig = (int)fig, ib = (int)fib;

        const uint4* C = ((const uint4*)cells) + (((size_t)(ib * 1024 + ig * 32 + ir)) << 1);
        uint4 w0 = C[0];   // corners (0,0,0),(0,0,1),(0,1,0),(0,1,1)
        uint4 w1 = C[1];   // corners (1,0,0),(1,0,1),(1,1,0),(1,1,1)

        // interpolate in code space (affine-invariant), then one fma per channel
        float x00 = LERP(CH0(w0.x), CH0(w0.y), fr), x01 = LERP(CH0(w0.z), CH0(w0.w), fr);
        float x10 = LERP(CH0(w1.x), CH0(w1.y), fr), x11 = LERP(CH0(w1.z), CH0(w1.w), fr);
        float xc  = LERP(LERP(x00, x01, fg), LERP(x10, x11, fg), fb);
        ox[u] = fmaf(xc, st01, mn);

        float y00 = LERP(CH1(w0.x), CH1(w0.y), fr), y01 = LERP(CH1(w0.z), CH1(w0.w), fr);
        float y10 = LERP(CH1(w1.x), CH1(w1.y), fr), y11 = LERP(CH1(w1.z), CH1(w1.w), fr);
        float yc  = LERP(LERP(y00, y01, fg), LERP(y10, y11, fg), fb);
        oy[u] = fmaf(yc, st01, mn);

        float z00 = LERP(CH2(w0.x), CH2(w0.y), fr), z01 = LERP(CH2(w0.z), CH2(w0.w), fr);
        float z10 = LERP(CH2(w1.x), CH2(w1.y), fr), z11 = LERP(CH2(w1.z), CH2(w1.w), fr);
        float zc  = LERP(LERP(z00, z01, fg), LERP(z10, z11, fg), fb);
        oz[u] = fmaf(zc, st2, mn);
    }

    *(float4*)(out + p)          = make_float4(ox[0], ox[1], ox[2], ox[3]);
    *(float4*)(out + NP + p)     = make_float4(oy[0], oy[1], oy[2], oy[3]);
    *(float4*)(out + 2 * NP + p) = make_float4(oz[0], oz[1], oz[2], oz[3]);
}

extern "C" void kernel_launch(void* const* d_in, const int* in_sizes, int n_in,
                              void* d_out, int out_size, void* d_ws, size_t ws_size,
                              hipStream_t stream) {
    const float* img   = (const float*)d_in[0];
    const float* param = (const float*)d_in[1];
    const float* W0 = (const float*)d_in[2];
    const float* b0 = (const float*)d_in[3];
    const float* W1 = (const float*)d_in[4];
    const float* b1 = (const float*)d_in[5];
    const float* W2 = (const float*)d_in[6];
    const float* b2 = (const float*)d_in[7];
    const float* W3 = (const float*)d_in[8];
    const float* b3 = (const float*)d_in[9];
    const float* W4 = (const float*)d_in[10];
    const float* b4 = (const float*)d_in[11];

    short*    P     = (short*)d_ws;
    float*    lut4  = (float*)((char*)d_ws + LUT_BYTE_OFF);
    unsigned* rng   = (unsigned*)((char*)d_ws + RNG_BYTE_OFF);
    unsigned* cells = (unsigned*)((char*)d_ws + CELL_BYTE_OFF);
    float*    out   = (float*)d_out;

    hipLaunchKernelGGL(pack_weights_kernel, dim3(102), dim3(TPB), 0, stream,
                       W0, W1, W2, W3, W4, P, rng);

    int lut_blocks = (NPTS + 31) / 32;     // 1124
    hipLaunchKernelGGL(nilut_mfma_kernel, dim3(lut_blocks), dim3(TPB), 0, stream,
                       param, P, b0, b1, b2, b3, b4, lut4, rng);

    hipLaunchKernelGGL(expand_cells_kernel, dim3(1024), dim3(TPB), 0, stream,
                       lut4, rng, cells);

    const int NP = 2160 * 3840;
    int apply_blocks = (NP / 4 + TPB - 1) / TPB;   // 8100
    hipLaunchKernelGGL(apply_lut_kernel, dim3(apply_blocks), dim3(TPB), 0, stream,
                       img, cells, rng, out);
}